// Round 1
// baseline (2283.059 us; speedup 1.0000x reference)
//
#include <hip/hip_runtime.h>

#define NN 100000   // nodes
#define RR 8        // relations
#define BB 8        // bases
#define DD 128      // hidden dim
#define EE 800000   // edges

// ---------------------------------------------------------------------------
// Bucketing / counting kernels (run once per call; shared by both layers)
// ---------------------------------------------------------------------------

__global__ __launch_bounds__(256) void k_hist_cnt(const int* __restrict__ ei,
                                                  const int* __restrict__ et,
                                                  int* __restrict__ hist,
                                                  int* __restrict__ cnt) {
    __shared__ int lh[RR];
    if (threadIdx.x < RR) lh[threadIdx.x] = 0;
    __syncthreads();
    int e = blockIdx.x * 256 + threadIdx.x;
    if (e < EE) {
        int r = et[e];
        int d = ei[EE + e];                 // edge_index[1][e] = dst
        atomicAdd(&lh[r], 1);               // LDS-local histogram
        atomicAdd(&cnt[d * RR + r], 1);     // per-(dst,rel) count
    }
    __syncthreads();
    if (threadIdx.x < RR && lh[threadIdx.x] > 0)
        atomicAdd(&hist[threadIdx.x], lh[threadIdx.x]);
}

__global__ void k_prefix(const int* __restrict__ hist, int* __restrict__ offsets) {
    if (threadIdx.x == 0 && blockIdx.x == 0) {
        int s = 0;
        for (int r = 0; r < RR; ++r) { offsets[r] = s; s += hist[r]; }
        offsets[RR] = s;
    }
}

__global__ __launch_bounds__(256) void k_bucket(const int* __restrict__ ei,
                                                const int* __restrict__ et,
                                                const int* __restrict__ offsets,
                                                int* __restrict__ cursor,
                                                int* __restrict__ srcs,
                                                int* __restrict__ dsts) {
    __shared__ int lcnt[RR];
    __shared__ int lbase[RR];
    if (threadIdx.x < RR) lcnt[threadIdx.x] = 0;
    __syncthreads();
    int e = blockIdx.x * 256 + threadIdx.x;
    int r = 0, myslot = 0;
    if (e < EE) {
        r = et[e];
        myslot = atomicAdd(&lcnt[r], 1);
    }
    __syncthreads();
    if (threadIdx.x < RR)
        lbase[threadIdx.x] = atomicAdd(&cursor[threadIdx.x], lcnt[threadIdx.x]);
    __syncthreads();
    if (e < EE) {
        int pos = offsets[r] + lbase[r] + myslot;
        srcs[pos] = ei[e];
        dsts[pos] = ei[EE + e];
    }
}

__global__ __launch_bounds__(256) void k_invcnt(const int* __restrict__ cnt,
                                                float* __restrict__ invc) {
    int i = blockIdx.x * 256 + threadIdx.x;
    if (i < NN * RR) {
        int c = cnt[i];
        invc[i] = 1.0f / (float)(c > 1 ? c : 1);
    }
}

// W[r][i][o] = sum_b comp[r][b] * basis[b][i][o]
__global__ __launch_bounds__(256) void k_W(const float* __restrict__ comp,
                                           const float* __restrict__ basis,
                                           float* __restrict__ W) {
    int idx = blockIdx.x * 256 + threadIdx.x;   // over RR*DD*DD = 131072
    int r = idx >> 14;                          // / (DD*DD)
    int io = idx & 16383;
    float s = 0.f;
#pragma unroll
    for (int b = 0; b < BB; ++b)
        s += comp[r * BB + b] * basis[b * (DD * DD) + io];
    W[idx] = s;
}

// ---------------------------------------------------------------------------
// Dense base: out[n] = act(x[n]) @ root + bias     (full write, no atomics)
// ---------------------------------------------------------------------------

#define FMA4(Y, XA)                                                  \
    Y.x = fmaf(XA.x, w0.x, Y.x); Y.y = fmaf(XA.x, w0.y, Y.y);        \
    Y.x = fmaf(XA.y, w1.x, Y.x); Y.y = fmaf(XA.y, w1.y, Y.y);        \
    Y.x = fmaf(XA.z, w2.x, Y.x); Y.y = fmaf(XA.z, w2.y, Y.y);        \
    Y.x = fmaf(XA.w, w3.x, Y.x); Y.y = fmaf(XA.w, w3.y, Y.y);

template <bool RELU>
__global__ __launch_bounds__(256) void k_base(const float* __restrict__ x,
                                              const float* __restrict__ root,
                                              const float* __restrict__ bias,
                                              float* __restrict__ out) {
    __shared__ float Ws[DD * DD];        // 64 KB
    __shared__ float xs[4][4][DD];       // 8 KB (per-wave staging)
    for (int i = threadIdx.x; i < DD * DD / 4; i += 256)
        ((float4*)Ws)[i] = ((const float4*)root)[i];
    __syncthreads();
    const int wave = threadIdx.x >> 6, lane = threadIdx.x & 63;
    const float2 bv = ((const float2*)bias)[lane];
    const int base = blockIdx.x * 64;
    const int nend = min(base + 64, NN);
    for (int ng = base + wave * 4; ng < nend; ng += 16) {
        const int m = min(4, nend - ng);
#pragma unroll
        for (int j = 0; j < 4; ++j) {
            int n = ng + (j < m ? j : 0);
            float2 t = ((const float2*)(x + (size_t)n * DD))[lane];
            if (RELU) { t.x = fmaxf(t.x, 0.f); t.y = fmaxf(t.y, 0.f); }
            *(float2*)&xs[wave][j][2 * lane] = t;
        }
        float2 y0 = {0.f, 0.f}, y1 = {0.f, 0.f}, y2 = {0.f, 0.f}, y3 = {0.f, 0.f};
        for (int i = 0; i < DD; i += 4) {
            float4 xa = *(const float4*)&xs[wave][0][i];
            float4 xb = *(const float4*)&xs[wave][1][i];
            float4 xc = *(const float4*)&xs[wave][2][i];
            float4 xd = *(const float4*)&xs[wave][3][i];
            float2 w0 = *(const float2*)&Ws[(i + 0) * DD + 2 * lane];
            float2 w1 = *(const float2*)&Ws[(i + 1) * DD + 2 * lane];
            float2 w2 = *(const float2*)&Ws[(i + 2) * DD + 2 * lane];
            float2 w3 = *(const float2*)&Ws[(i + 3) * DD + 2 * lane];
            FMA4(y0, xa) FMA4(y1, xb) FMA4(y2, xc) FMA4(y3, xd)
        }
        float2 r0 = {y0.x + bv.x, y0.y + bv.y};
        *(float2*)&out[(size_t)(ng + 0) * DD + 2 * lane] = r0;
        if (m > 1) { float2 r1 = {y1.x + bv.x, y1.y + bv.y};
                     *(float2*)&out[(size_t)(ng + 1) * DD + 2 * lane] = r1; }
        if (m > 2) { float2 r2 = {y2.x + bv.x, y2.y + bv.y};
                     *(float2*)&out[(size_t)(ng + 2) * DD + 2 * lane] = r2; }
        if (m > 3) { float2 r3 = {y3.x + bv.x, y3.y + bv.y};
                     *(float2*)&out[(size_t)(ng + 3) * DD + 2 * lane] = r3; }
    }
}

// ---------------------------------------------------------------------------
// Edge transform + scatter: out[dst] += (act(x[src]) @ W[rel]) * inv_cnt
// blockIdx.y = relation; W[rel] cached in LDS; 4 edges per wave per group.
// ---------------------------------------------------------------------------

template <bool RELU>
__global__ __launch_bounds__(256) void k_edge(const float* __restrict__ x,
                                              const float* __restrict__ W,
                                              const int* __restrict__ srcs,
                                              const int* __restrict__ dsts,
                                              const int* __restrict__ offsets,
                                              const float* __restrict__ invc,
                                              float* __restrict__ out) {
    __shared__ float Ws[DD * DD];        // 64 KB
    __shared__ float xs[4][4][DD];       // 8 KB
    const int r = blockIdx.y;
    const int lo = offsets[r], hi = offsets[r + 1];
    const int cstart = lo + blockIdx.x * 256;
    if (cstart >= hi) return;
    const float* Wr = W + (size_t)r * DD * DD;
    for (int i = threadIdx.x; i < DD * DD / 4; i += 256)
        ((float4*)Ws)[i] = ((const float4*)Wr)[i];
    __syncthreads();
    const int wave = threadIdx.x >> 6, lane = threadIdx.x & 63;
    const int cend = min(hi, cstart + 256);
    for (int eg = cstart + wave * 4; eg < cend; eg += 16) {
        const int m = min(4, cend - eg);
        float sc[4]; int dn[4];
#pragma unroll
        for (int j = 0; j < 4; ++j) {
            int e = eg + (j < m ? j : 0);
            int s = srcs[e];
            dn[j] = dsts[e];
            sc[j] = (j < m) ? invc[(size_t)dn[j] * RR + r] : 0.f;
            float2 t = ((const float2*)(x + (size_t)s * DD))[lane];
            if (RELU) { t.x = fmaxf(t.x, 0.f); t.y = fmaxf(t.y, 0.f); }
            *(float2*)&xs[wave][j][2 * lane] = t;
        }
        float2 y0 = {0.f, 0.f}, y1 = {0.f, 0.f}, y2 = {0.f, 0.f}, y3 = {0.f, 0.f};
        for (int i = 0; i < DD; i += 4) {
            float4 xa = *(const float4*)&xs[wave][0][i];
            float4 xb = *(const float4*)&xs[wave][1][i];
            float4 xc = *(const float4*)&xs[wave][2][i];
            float4 xd = *(const float4*)&xs[wave][3][i];
            float2 w0 = *(const float2*)&Ws[(i + 0) * DD + 2 * lane];
            float2 w1 = *(const float2*)&Ws[(i + 1) * DD + 2 * lane];
            float2 w2 = *(const float2*)&Ws[(i + 2) * DD + 2 * lane];
            float2 w3 = *(const float2*)&Ws[(i + 3) * DD + 2 * lane];
            FMA4(y0, xa) FMA4(y1, xb) FMA4(y2, xc) FMA4(y3, xd)
        }
        {
            float* o = out + (size_t)dn[0] * DD + 2 * lane;
            unsafeAtomicAdd(o, y0.x * sc[0]); unsafeAtomicAdd(o + 1, y0.y * sc[0]);
        }
        if (m > 1) { float* o = out + (size_t)dn[1] * DD + 2 * lane;
                     unsafeAtomicAdd(o, y1.x * sc[1]); unsafeAtomicAdd(o + 1, y1.y * sc[1]); }
        if (m > 2) { float* o = out + (size_t)dn[2] * DD + 2 * lane;
                     unsafeAtomicAdd(o, y2.x * sc[2]); unsafeAtomicAdd(o + 1, y2.y * sc[2]); }
        if (m > 3) { float* o = out + (size_t)dn[3] * DD + 2 * lane;
                     unsafeAtomicAdd(o, y3.x * sc[3]); unsafeAtomicAdd(o + 1, y3.y * sc[3]); }
    }
}

// ---------------------------------------------------------------------------

extern "C" void kernel_launch(void* const* d_in, const int* in_sizes, int n_in,
                              void* d_out, int out_size, void* d_ws, size_t ws_size,
                              hipStream_t stream) {
    const int*   ei     = (const int*)d_in[0];
    const int*   et     = (const int*)d_in[1];
    const float* emb    = (const float*)d_in[2];
    const float* basis1 = (const float*)d_in[3];
    const float* comp1  = (const float*)d_in[4];
    const float* root1  = (const float*)d_in[5];
    const float* bias1  = (const float*)d_in[6];
    const float* basis2 = (const float*)d_in[7];
    const float* comp2  = (const float*)d_in[8];
    const float* root2  = (const float*)d_in[9];
    const float* bias2  = (const float*)d_in[10];
    float* out = (float*)d_out;

    char* ws = (char*)d_ws;
    // layout (bytes): [hist 32 | cursor 32 | cnt 3.2MB] zeroed together
    int*   hist    = (int*)ws;
    int*   cursor  = hist + RR;
    int*   cnt     = cursor + RR;
    size_t zbytes  = (size_t)(RR + RR + NN * RR) * sizeof(int);
    int*   offsets = (int*)(ws + 3200256);
    float* invc    = (float*)(ws + 3200512);      // 3.2 MB
    int*   srcs    = (int*)(ws + 6400512);        // 3.2 MB
    int*   dsts    = (int*)(ws + 9600512);        // 3.2 MB
    float* W1      = (float*)(ws + 12800512);     // 512 KB
    float* W2      = (float*)(ws + 13324800);     // 512 KB
    float* h1      = (float*)(ws + 13849088);     // 51.2 MB

    hipMemsetAsync(ws, 0, zbytes, stream);

    k_hist_cnt<<<(EE + 255) / 256, 256, 0, stream>>>(ei, et, hist, cnt);
    k_prefix<<<1, 64, 0, stream>>>(hist, offsets);
    k_bucket<<<(EE + 255) / 256, 256, 0, stream>>>(ei, et, offsets, cursor, srcs, dsts);
    k_invcnt<<<(NN * RR + 255) / 256, 256, 0, stream>>>(cnt, invc);

    k_W<<<RR * DD * DD / 256, 256, 0, stream>>>(comp1, basis1, W1);
    k_W<<<RR * DD * DD / 256, 256, 0, stream>>>(comp2, basis2, W2);

    dim3 egrid((EE + 255) / 256, RR);

    // layer 1: h1 = emb@root1 + bias1 + scatter(edge transforms)   (pre-ReLU)
    k_base<false><<<(NN + 63) / 64, 256, 0, stream>>>(emb, root1, bias1, h1);
    k_edge<false><<<egrid, 256, 0, stream>>>(emb, W1, srcs, dsts, offsets, invc, h1);

    // layer 2: out = relu(h1)@root2 + bias2 + scatter(relu-edge transforms)
    k_base<true><<<(NN + 63) / 64, 256, 0, stream>>>(h1, root2, bias2, out);
    k_edge<true><<<egrid, 256, 0, stream>>>(h1, W2, srcs, dsts, offsets, invc, out);
}

// Round 2
// 741.532 us; speedup vs baseline: 3.0788x; 3.0788x over previous
//
#include <hip/hip_runtime.h>

#define NN 100000   // nodes
#define RR 8        // relations
#define BB 8        // bases
#define DD 128      // hidden dim
#define EE 800000   // edges
#define KT 1152     // 128 (root) + 8*128 (relations)
#define NSEG (NN * RR)   // 800000 segments (== EE, convenient for scan grids)
#define ASTR 40     // LDS tile row stride in bf16 (pad 32->40: <=2-way banks, 16B aligned)

typedef __attribute__((ext_vector_type(8))) __bf16 bf16x8;
typedef __attribute__((ext_vector_type(4))) float f32x4;
typedef __attribute__((ext_vector_type(4))) unsigned int u32x4;

__device__ __forceinline__ unsigned short f2bf(float f) {
    unsigned u = __float_as_uint(f);
    u += 0x7fffu + ((u >> 16) & 1u);          // round-to-nearest-even
    return (unsigned short)(u >> 16);
}
__device__ __forceinline__ float bf2f(unsigned short h) {
    return __uint_as_float(((unsigned)h) << 16);
}

// ---------------------------------------------------------------------------
// Counting sort of edges by key = dst*RR + rel  (shared by both layers)
// ---------------------------------------------------------------------------

__global__ __launch_bounds__(256) void k_cnt(const int* __restrict__ ei,
                                             const int* __restrict__ et,
                                             int* __restrict__ cnt) {
    int e = blockIdx.x * 256 + threadIdx.x;
    if (e < EE) atomicAdd(&cnt[ei[EE + e] * RR + et[e]], 1);
}

__global__ __launch_bounds__(256) void k_scan_local(const int* __restrict__ cnt,
                                                    int* __restrict__ loc,
                                                    int* __restrict__ bsum) {
    __shared__ int tmp[256];
    int t = threadIdx.x, i = blockIdx.x * 256 + t;
    int v = cnt[i];
    tmp[t] = v; __syncthreads();
    int val = v;
#pragma unroll
    for (int d = 1; d < 256; d <<= 1) {
        int a = (t >= d) ? tmp[t - d] : 0;
        __syncthreads();
        val += a; tmp[t] = val;
        __syncthreads();
    }
    loc[i] = val - v;                       // block-local exclusive
    if (t == 255) bsum[blockIdx.x] = val;   // block total
}

__global__ void k_scan_bsum(const int* __restrict__ bsum, int* __restrict__ boff) {
    __shared__ int tmp[256];
    const int NB = EE / 256;                // 3125
    const int CH = 13;                      // 256*13 >= 3125
    int t = threadIdx.x;
    int base = t * CH, s = 0;
    for (int j = 0; j < CH; ++j) { int idx = base + j; if (idx < NB) s += bsum[idx]; }
    tmp[t] = s; __syncthreads();
    int val = s;
#pragma unroll
    for (int d = 1; d < 256; d <<= 1) {
        int a = (t >= d) ? tmp[t - d] : 0;
        __syncthreads();
        val += a; tmp[t] = val;
        __syncthreads();
    }
    int run = val - s;                      // exclusive over chunks
    for (int j = 0; j < CH; ++j) { int idx = base + j; if (idx < NB) { boff[idx] = run; run += bsum[idx]; } }
}

__global__ __launch_bounds__(256) void k_scan_add(int* __restrict__ loc,
                                                  const int* __restrict__ boff) {
    int i = blockIdx.x * 256 + threadIdx.x; // NSEG threads exactly
    loc[i] += boff[i >> 8];
}

__global__ __launch_bounds__(256) void k_scatter(const int* __restrict__ ei,
                                                 const int* __restrict__ et,
                                                 const int* __restrict__ segoff,
                                                 int* __restrict__ cursor,
                                                 int* __restrict__ srcs) {
    int e = blockIdx.x * 256 + threadIdx.x;
    if (e < EE) {
        int key = ei[EE + e] * RR + et[e];
        int pos = segoff[key] + atomicAdd(&cursor[key], 1);
        srcs[pos] = ei[e];
    }
}

// ---------------------------------------------------------------------------
// B matrix prep: BT[o][k] bf16 hi/lo, k<128 -> root, else W[r][i][o]
// ---------------------------------------------------------------------------

__global__ __launch_bounds__(256) void k_prepB(const float* __restrict__ root,
                                               const float* __restrict__ comp,
                                               const float* __restrict__ basis,
                                               unsigned short* __restrict__ Bhi,
                                               unsigned short* __restrict__ Blo) {
    int idx = blockIdx.x * 256 + threadIdx.x;   // DD*KT = 147456
    if (idx >= DD * KT) return;
    int o = idx / KT, k = idx - o * KT;
    float v;
    if (k < DD) {
        v = root[k * DD + o];
    } else {
        int r = (k - DD) >> 7, i = (k - DD) & 127;
        float s = 0.f;
#pragma unroll
        for (int b = 0; b < BB; ++b)
            s += comp[r * BB + b] * basis[((size_t)b * DD + i) * DD + o];
        v = s;
    }
    unsigned short hi = f2bf(v);
    unsigned short lo = f2bf(v - bf2f(hi));
    Bhi[idx] = hi;
    Blo[idx] = lo;
}

// ---------------------------------------------------------------------------
// Fused agg + GEMM:  out = [act(x) | seg-mean act(x[src])] @ (Bhi + Blo) + bias
// Block: 128 nodes x 128 outputs, K-loop of 36 steps of 32.
// A-tile built on the fly in LDS (x slice or segment gather-sum), bf16.
// MFMA 16x16x32_bf16, f32 accumulate; B hi/lo compensated.
// ---------------------------------------------------------------------------

template <bool RELU>
__global__ __launch_bounds__(256, 2) void k_gemm(const float* __restrict__ x,
                                                 const unsigned short* __restrict__ Bhi,
                                                 const unsigned short* __restrict__ Blo,
                                                 const float* __restrict__ bias,
                                                 const int* __restrict__ srcs,
                                                 const int* __restrict__ segoff,
                                                 const int* __restrict__ segcnt,
                                                 float* __restrict__ out) {
    __shared__ unsigned short As[128 * ASTR];    // 10.2 KB
    __shared__ unsigned short Bhs[128 * ASTR];   // 10.2 KB
    __shared__ unsigned short Bls[128 * ASTR];   // 10.2 KB
    __shared__ int   sbeg[1024];
    __shared__ int   scnt[1024];
    __shared__ float sinv[1024];

    const int tid = threadIdx.x;
    const int M0 = blockIdx.x * 128;

    // segment metadata for this block's 128 nodes x 8 relations (contiguous keys)
#pragma unroll
    for (int p = 0; p < 4; ++p) {
        int i = p * 256 + tid;
        int g = M0 * RR + i;
        int b = 0, c = 0;
        if (g < NSEG) { b = segoff[g]; c = segcnt[g]; }
        sbeg[i] = b; scnt[i] = c;
        sinv[i] = 1.0f / (float)(c > 1 ? c : 1);
    }

    const int wave = tid >> 6, lane = tid & 63;
    const int quad = lane >> 4, lm = lane & 15;
    const int srow = tid >> 1, shalf = tid & 1;   // staging: 2 threads/node, 16 cols each

    f32x4 acc[2][8];
#pragma unroll
    for (int a = 0; a < 2; ++a)
#pragma unroll
        for (int b = 0; b < 8; ++b) acc[a][b] = (f32x4){0.f, 0.f, 0.f, 0.f};

    __syncthreads();

    for (int ks = 0; ks < KT / 32; ++ks) {
        const int k0 = ks * 32;

        // ---- stage A-tile: 128 rows x 32 bf16
        float v[16];
        if (ks < 4) {                    // x (root) block
            int nidx = M0 + srow; if (nidx >= NN) nidx = NN - 1;
            const float4* px = (const float4*)(x + (size_t)nidx * DD + k0 + shalf * 16);
#pragma unroll
            for (int j = 0; j < 4; ++j) {
                float4 t = px[j];
                if (RELU) { t.x = fmaxf(t.x, 0.f); t.y = fmaxf(t.y, 0.f);
                            t.z = fmaxf(t.z, 0.f); t.w = fmaxf(t.w, 0.f); }
                v[4 * j + 0] = t.x; v[4 * j + 1] = t.y; v[4 * j + 2] = t.z; v[4 * j + 3] = t.w;
            }
        } else {                         // relation r, cols i0..i0+32 of segment mean
            const int r  = (ks - 4) >> 2;
            const int i0 = ((ks - 4) & 3) * 32;
            const int si = srow * RR + r;
            const int beg = sbeg[si], c = scnt[si];
#pragma unroll
            for (int j = 0; j < 16; ++j) v[j] = 0.f;
            for (int e = 0; e < c; ++e) {
                int s = srcs[beg + e];
                const float4* px = (const float4*)(x + (size_t)s * DD + i0 + shalf * 16);
#pragma unroll
                for (int j = 0; j < 4; ++j) {
                    float4 t = px[j];
                    if (RELU) { t.x = fmaxf(t.x, 0.f); t.y = fmaxf(t.y, 0.f);
                                t.z = fmaxf(t.z, 0.f); t.w = fmaxf(t.w, 0.f); }
                    v[4 * j + 0] += t.x; v[4 * j + 1] += t.y; v[4 * j + 2] += t.z; v[4 * j + 3] += t.w;
                }
            }
            const float iv = sinv[si];
#pragma unroll
            for (int j = 0; j < 16; ++j) v[j] *= iv;
        }
        {
            unsigned pk[8];
#pragma unroll
            for (int j = 0; j < 8; ++j)
                pk[j] = (unsigned)f2bf(v[2 * j]) | ((unsigned)f2bf(v[2 * j + 1]) << 16);
            unsigned short* pa = &As[srow * ASTR + shalf * 16];
            ((u32x4*)pa)[0] = (u32x4){pk[0], pk[1], pk[2], pk[3]};
            ((u32x4*)pa)[1] = (u32x4){pk[4], pk[5], pk[6], pk[7]};
        }

        // ---- stage B-tiles (hi/lo), transposed layout BT[o][k]
#pragma unroll
        for (int p = 0; p < 2; ++p) {
            int c2 = p * 256 + tid;           // 512 chunks of 16B
            int o = c2 >> 2, q = c2 & 3;
            int goff = o * KT + k0 + q * 8;
            u32x4 bh = *(const u32x4*)(Bhi + goff);
            u32x4 bl = *(const u32x4*)(Blo + goff);
            *(u32x4*)&Bhs[o * ASTR + q * 8] = bh;
            *(u32x4*)&Bls[o * ASTR + q * 8] = bl;
        }
        __syncthreads();

        // ---- compute: 2 m-tiles x 8 n-tiles, B hi+lo
        bf16x8 af0 = __builtin_bit_cast(bf16x8, *(const u32x4*)&As[(wave * 32 + lm) * ASTR + quad * 8]);
        bf16x8 af1 = __builtin_bit_cast(bf16x8, *(const u32x4*)&As[(wave * 32 + 16 + lm) * ASTR + quad * 8]);
#pragma unroll
        for (int nt = 0; nt < 8; ++nt) {
            bf16x8 bh = __builtin_bit_cast(bf16x8, *(const u32x4*)&Bhs[(nt * 16 + lm) * ASTR + quad * 8]);
            bf16x8 bl = __builtin_bit_cast(bf16x8, *(const u32x4*)&Bls[(nt * 16 + lm) * ASTR + quad * 8]);
            acc[0][nt] = __builtin_amdgcn_mfma_f32_16x16x32_bf16(af0, bh, acc[0][nt], 0, 0, 0);
            acc[0][nt] = __builtin_amdgcn_mfma_f32_16x16x32_bf16(af0, bl, acc[0][nt], 0, 0, 0);
            acc[1][nt] = __builtin_amdgcn_mfma_f32_16x16x32_bf16(af1, bh, acc[1][nt], 0, 0, 0);
            acc[1][nt] = __builtin_amdgcn_mfma_f32_16x16x32_bf16(af1, bl, acc[1][nt], 0, 0, 0);
        }
        __syncthreads();
    }

    // ---- epilogue: bias + guarded store (C/D: col=lane&15, row=quad*4+reg)
#pragma unroll
    for (int mt = 0; mt < 2; ++mt) {
#pragma unroll
        for (int nt = 0; nt < 8; ++nt) {
#pragma unroll
            for (int rg = 0; rg < 4; ++rg) {
                int row = M0 + wave * 32 + mt * 16 + quad * 4 + rg;
                int col = nt * 16 + lm;
                if (row < NN) out[(size_t)row * DD + col] = acc[mt][nt][rg] + bias[col];
            }
        }
    }
}

// ---------------------------------------------------------------------------

extern "C" void kernel_launch(void* const* d_in, const int* in_sizes, int n_in,
                              void* d_out, int out_size, void* d_ws, size_t ws_size,
                              hipStream_t stream) {
    const int*   ei     = (const int*)d_in[0];
    const int*   et     = (const int*)d_in[1];
    const float* emb    = (const float*)d_in[2];
    const float* basis1 = (const float*)d_in[3];
    const float* comp1  = (const float*)d_in[4];
    const float* root1  = (const float*)d_in[5];
    const float* bias1  = (const float*)d_in[6];
    const float* basis2 = (const float*)d_in[7];
    const float* comp2  = (const float*)d_in[8];
    const float* root2  = (const float*)d_in[9];
    const float* bias2  = (const float*)d_in[10];
    float* out = (float*)d_out;
    (void)in_sizes; (void)n_in; (void)out_size; (void)ws_size;

    char* ws = (char*)d_ws;
    int*            cnt    = (int*)(ws + 0);           // 3.2 MB
    int*            cursor = (int*)(ws + 3200000);     // 3.2 MB (zeroed with cnt)
    int*            segoff = (int*)(ws + 6400000);     // 3.2 MB (loc -> segoff in place)
    int*            srcs   = (int*)(ws + 9600000);     // 3.2 MB
    int*            bsum   = (int*)(ws + 12800000);    // 16 KB
    int*            boff   = (int*)(ws + 12816000);    // 16 KB
    unsigned short* Bhi1   = (unsigned short*)(ws + 12832000);   // 294912 B
    unsigned short* Blo1   = (unsigned short*)(ws + 13126912);
    unsigned short* Bhi2   = (unsigned short*)(ws + 13421824);
    unsigned short* Blo2   = (unsigned short*)(ws + 13716736);
    float*          h1     = (float*)(ws + 14011648);  // 51.2 MB -> end ~65.2 MB

    hipMemsetAsync(ws, 0, 6400000, stream);            // cnt + cursor

    k_cnt       <<<EE / 256, 256, 0, stream>>>(ei, et, cnt);
    k_scan_local<<<NSEG / 256, 256, 0, stream>>>(cnt, segoff, bsum);
    k_scan_bsum <<<1, 256, 0, stream>>>(bsum, boff);
    k_scan_add  <<<NSEG / 256, 256, 0, stream>>>(segoff, boff);
    k_scatter   <<<EE / 256, 256, 0, stream>>>(ei, et, segoff, cursor, srcs);

    k_prepB<<<(DD * KT + 255) / 256, 256, 0, stream>>>(root1, comp1, basis1, Bhi1, Blo1);
    k_prepB<<<(DD * KT + 255) / 256, 256, 0, stream>>>(root2, comp2, basis2, Bhi2, Blo2);

    const int gm = (NN + 127) / 128;   // 782
    k_gemm<false><<<gm, 256, 0, stream>>>(emb, Bhi1, Blo1, bias1, srcs, segoff, cnt, h1);
    k_gemm<true> <<<gm, 256, 0, stream>>>(h1,  Bhi2, Blo2, bias2, srcs, segoff, cnt, out);
}